// Round 4
// baseline (478.413 us; speedup 1.0000x reference)
//
#include <hip/hip_runtime.h>

typedef __attribute__((ext_vector_type(8))) short short8_t;
typedef __attribute__((ext_vector_type(4))) float f32x4;

#define MASK_VAL (-4294967295.0f)
#define NEG_BIG  (-1e30f)

__device__ __forceinline__ short f2bf(float x) {
    unsigned u;
    __builtin_memcpy(&u, &x, 4);
    u += 0x7FFFu + ((u >> 16) & 1u);   // round-to-nearest-even
    return (short)(u >> 16);
}
__device__ __forceinline__ float bf2f(short s) {
    unsigned u = ((unsigned)(unsigned short)s) << 16;
    float f;
    __builtin_memcpy(&f, &u, 4);
    return f;
}

// ---------------- prep (single launch): block 0 folds weights; blocks 1.. compute csAll
// ws layout (bytes):
//   0     : wkT   bf16 [64][64]  (W1b - W1c)^T   (row n, col k)
//   8192  : wdT   bf16 [64][64]  (W1d)^T
//   16384 : w2T   bf16 [32][64]  (W2)^T          (row o, col h)
//   36864 : csAll f32  [B][64]   b1 + q_b @ (W1a+W1c)
__global__ __launch_bounds__(256) void prep_all(
    const float* __restrict__ W1, const float* __restrict__ W2,
    const float* __restrict__ query, const float* __restrict__ b1,
    void* __restrict__ ws, int B)
{
    short* wkT = (short*)ws;
    short* wdT = wkT + 4096;
    short* w2T = wkT + 8192;
    float* csAll = (float*)((char*)ws + 36864);
    const int tid = threadIdx.x;

    if (blockIdx.x == 0) {
        for (int idx = tid; idx < 4096; idx += 256) {
            int n = idx & 63, k = idx >> 6;
            float a  = W1[4096  + idx];   // W1b[k][n]
            float c  = W1[8192  + idx];   // W1c[k][n]
            float d  = W1[12288 + idx];   // W1d[k][n]
            wkT[n * 64 + k] = f2bf(a - c);
            wdT[n * 64 + k] = f2bf(d);
        }
        for (int idx = tid; idx < 2048; idx += 256) {
            int o = idx & 31, h = idx >> 5;
            w2T[o * 64 + h] = f2bf(W2[idx]);   // W2[h][o], idx = h*32+o
        }
        return;
    }

    // csAll for 16 batches per block; wac built locally (no dependency on block 0)
    __shared__ float wacs[4096];     // 16 KB: W1a + W1c  (i-major)
    __shared__ float qsb[16 * 64];   // 4 KB
    __shared__ float b1s[64];
    const int g0 = (blockIdx.x - 1) * 16;
    for (int idx = tid; idx < 4096; idx += 256)
        wacs[idx] = W1[idx] + W1[8192 + idx];
    {
        int nb = B - g0; if (nb > 16) nb = 16;
        if (nb > 0)
            for (int i = tid; i < nb * 16; i += 256)
                ((float4*)qsb)[i] = ((const float4*)(query + (size_t)g0 * 64))[i];
    }
    if (tid < 64) b1s[tid] = b1[tid];
    __syncthreads();
    for (int o = tid; o < 1024; o += 256) {
        int bb = o >> 6, h = o & 63;
        if (g0 + bb >= B) continue;
        float acc = b1s[h];
#pragma unroll 16
        for (int i = 0; i < 64; ++i)
            acc += qsb[bb * 64 + i] * wacs[i * 64 + h];
        csAll[(size_t)(g0 + bb) * 64 + h] = acc;
    }
}

// ---------------- main: one WAVE per batch, online softmax, depth-2 key prefetch ----
__global__ __launch_bounds__(256, 3) void attn_main(
    const float* __restrict__ query,    // (B,1,64)
    const float* __restrict__ keys,     // (B,200,64)
    const int*   __restrict__ keys_len, // (B,1)
    const float* __restrict__ b2,       // (32)
    const float* __restrict__ W3,       // (32,1)
    const float* __restrict__ b3,       // (1)
    const void*  __restrict__ ws,
    float* __restrict__ out,            // (B,1,64)
    int B)
{
    constexpr int STR = 72;   // shorts; 144 B row stride -> 16B-aligned b128 everywhere
    const short* wkT   = (const short*)ws;
    const short* wdT   = wkT + 4096;
    const short* w2T   = wkT + 8192;
    const float* csAll = (const float*)((const char*)ws + 36864);

    __shared__ short Bk[64 * STR];      // (W1b-W1c)^T
    __shared__ short Bd[64 * STR];      // W1d^T
    __shared__ short W2s[32 * STR];     // W2^T (rows o, cols h)
    __shared__ short h1w[4][16 * STR];  // per-wave h1 tile (C-layout -> B-frag layout)

    const int tid  = threadIdx.x;
    const int lane = tid & 63;
    const int wid  = tid >> 6;
    const int col  = lane & 15;
    const int quad = lane >> 4;
    const int b    = blockIdx.x * 4 + wid;
    const bool act = (b < B);

    // ---- cooperative staging (once per block = per 4 batches) ----
    for (int c = tid; c < 512; c += 256) {
        int r = c >> 3, ch = (c & 7) * 8;
        *(short8_t*)&Bk[r * STR + ch] = *(const short8_t*)(wkT + r * 64 + ch);
        *(short8_t*)&Bd[r * STR + ch] = *(const short8_t*)(wdT + r * 64 + ch);
    }
    {
        int r = tid >> 3, ch = (tid & 7) * 8;
        *(short8_t*)&W2s[r * STR + ch] = *(const short8_t*)(w2T + r * 64 + ch);
    }

    // ---- per-wave prologue ----
    const float* kb = nullptr;
    float4 pA0, pA1, pA2, pA3;          // prefetch buffer A (tile jt even)
    float4 pB0, pB1, pB2, pB3;          // prefetch buffer B (tile jt odd)
    float4 qv0, qv1, qv2, qv3;
    float4 b2qa, b2qb, w3qa, w3qb;
    float cs0 = 0.f, cs1 = 0.f, cs2 = 0.f, cs3 = 0.f, b3v = 0.f;
    if (act) {
        kb = keys + (size_t)b * 12800;
        {   // tile 0 (rows 0..15)
            const float* kr = kb + col * 64 + quad * 8;
            pA0 = *(const float4*)(kr);
            pA1 = *(const float4*)(kr + 4);
            pA2 = *(const float4*)(kr + 32);
            pA3 = *(const float4*)(kr + 36);
        }
        {   // tile 1 (rows 16..31)
            const float* kr = kb + (16 + col) * 64 + quad * 8;
            pB0 = *(const float4*)(kr);
            pB1 = *(const float4*)(kr + 4);
            pB2 = *(const float4*)(kr + 32);
            pB3 = *(const float4*)(kr + 36);
        }
        const float* qb = query + (size_t)b * 64;
        qv0 = *(const float4*)(qb + quad * 8);
        qv1 = *(const float4*)(qb + quad * 8 + 4);
        qv2 = *(const float4*)(qb + 32 + quad * 8);
        qv3 = *(const float4*)(qb + 32 + quad * 8 + 4);
        const float* cb = csAll + (size_t)b * 64;
        cs0 = cb[col]; cs1 = cb[16 + col]; cs2 = cb[32 + col]; cs3 = cb[48 + col];
        b2qa = *(const float4*)(b2 + quad * 4);
        b2qb = *(const float4*)(b2 + 16 + quad * 4);
        w3qa = *(const float4*)(W3 + quad * 4);
        w3qb = *(const float4*)(W3 + 16 + quad * 4);
        b3v  = b3[0];
    }
    __syncthreads();          // the ONLY block-wide barrier
    if (!act) return;

    const int len = keys_len[b];
    short* hw = h1w[wid];

    float m_run = NEG_BIG, l_run = 0.f;
    float accv[16];
#pragma unroll
    for (int i = 0; i < 16; ++i) accv[i] = 0.f;

    // ---- one tile of 16 rows: GEMM1 -> h1 -> GEMM2(swapped) -> score -> online SM ----
    auto tile = [&](int jt, float4 k0, float4 k1, float4 k2, float4 k3) {
        short8_t aK0, aK1, aQ0, aQ1;
        aK0[0] = f2bf(k0.x); aK0[1] = f2bf(k0.y); aK0[2] = f2bf(k0.z); aK0[3] = f2bf(k0.w);
        aK0[4] = f2bf(k1.x); aK0[5] = f2bf(k1.y); aK0[6] = f2bf(k1.z); aK0[7] = f2bf(k1.w);
        aK1[0] = f2bf(k2.x); aK1[1] = f2bf(k2.y); aK1[2] = f2bf(k2.z); aK1[3] = f2bf(k2.w);
        aK1[4] = f2bf(k3.x); aK1[5] = f2bf(k3.y); aK1[6] = f2bf(k3.z); aK1[7] = f2bf(k3.w);
        aQ0[0] = f2bf(k0.x * qv0.x); aQ0[1] = f2bf(k0.y * qv0.y);
        aQ0[2] = f2bf(k0.z * qv0.z); aQ0[3] = f2bf(k0.w * qv0.w);
        aQ0[4] = f2bf(k1.x * qv1.x); aQ0[5] = f2bf(k1.y * qv1.y);
        aQ0[6] = f2bf(k1.z * qv1.z); aQ0[7] = f2bf(k1.w * qv1.w);
        aQ1[0] = f2bf(k2.x * qv2.x); aQ1[1] = f2bf(k2.y * qv2.y);
        aQ1[2] = f2bf(k2.z * qv2.z); aQ1[3] = f2bf(k2.w * qv2.w);
        aQ1[4] = f2bf(k3.x * qv3.x); aQ1[5] = f2bf(k3.y * qv3.y);
        aQ1[6] = f2bf(k3.z * qv3.z); aQ1[7] = f2bf(k3.w * qv3.w);

        f32x4 acc[4] = {f32x4{0,0,0,0}, f32x4{0,0,0,0}, f32x4{0,0,0,0}, f32x4{0,0,0,0}};
#pragma unroll
        for (int nt = 0; nt < 4; ++nt) {
            const short* bp = &Bk[(nt * 16 + col) * STR + quad * 8];
            const short* dp = &Bd[(nt * 16 + col) * STR + quad * 8];
            acc[nt] = __builtin_amdgcn_mfma_f32_16x16x32_bf16(aK0, *(const short8_t*)bp,        acc[nt], 0, 0, 0);
            acc[nt] = __builtin_amdgcn_mfma_f32_16x16x32_bf16(aK1, *(const short8_t*)(bp + 32), acc[nt], 0, 0, 0);
            acc[nt] = __builtin_amdgcn_mfma_f32_16x16x32_bf16(aQ0, *(const short8_t*)dp,        acc[nt], 0, 0, 0);
            acc[nt] = __builtin_amdgcn_mfma_f32_16x16x32_bf16(aQ1, *(const short8_t*)(dp + 32), acc[nt], 0, 0, 0);
        }

        // relu + cs -> per-wave h1 tile (intra-wave LDS, program-order safe)
        float csv[4] = {cs0, cs1, cs2, cs3};
#pragma unroll
        for (int nt = 0; nt < 4; ++nt) {
            float cadd = csv[nt];
#pragma unroll
            for (int r = 0; r < 4; ++r)
                hw[(quad * 4 + r) * STR + nt * 16 + col] = f2bf(fmaxf(acc[nt][r] + cadd, 0.f));
        }

        // GEMM2 SWAPPED: A = W2^T frags (m = o_local), B = h1 frags (n = t)
        // -> D2 col = t = lane&15, reg r: o = quad*4 + r  (transposed vs before)
        f32x4 acc2a = f32x4{0,0,0,0}, acc2b = f32x4{0,0,0,0};
#pragma unroll
        for (int ks = 0; ks < 2; ++ks) {
            short8_t h1f = *(const short8_t*)&hw[col * STR + ks * 32 + quad * 8];
            acc2a = __builtin_amdgcn_mfma_f32_16x16x32_bf16(
                *(const short8_t*)&W2s[col * STR + ks * 32 + quad * 8],        h1f, acc2a, 0, 0, 0);
            acc2b = __builtin_amdgcn_mfma_f32_16x16x32_bf16(
                *(const short8_t*)&W2s[(16 + col) * STR + ks * 32 + quad * 8], h1f, acc2b, 0, 0, 0);
        }

        // per-lane partial score over its 8 o-values, then 2 shuffles across quads
        float sp = 0.f;
#pragma unroll
        for (int r = 0; r < 4; ++r) {
            sp += fmaxf(acc2a[r] + b2qa[r], 0.f) * w3qa[r]
                + fmaxf(acc2b[r] + b2qb[r], 0.f) * w3qb[r];
        }
        sp += __shfl_xor(sp, 16);
        sp += __shfl_xor(sp, 32);
        float sv = sp + b3v;                  // every lane: score for row jt*16+col

        // ---- online softmax update ----
        int  row  = jt * 16 + col;
        bool vrow = row < 200;
        sv = (row < len) ? sv : MASK_VAL;     // mask (len==0 -> uniform, matches reference)
        float svm = vrow ? sv : NEG_BIG;
        svm = fmaxf(svm, __shfl_xor(svm, 1));
        svm = fmaxf(svm, __shfl_xor(svm, 2));
        svm = fmaxf(svm, __shfl_xor(svm, 4));
        svm = fmaxf(svm, __shfl_xor(svm, 8));
        float m_new = fmaxf(m_run, svm);
        float p = vrow ? __expf(sv - m_new) : 0.f;
        float ps = p;
        ps += __shfl_xor(ps, 1);
        ps += __shfl_xor(ps, 2);
        ps += __shfl_xor(ps, 4);
        ps += __shfl_xor(ps, 8);
        if (m_new > m_run) {                  // wave-uniform; rescale only when max grows
            float scale = __expf(m_run - m_new);
            l_run *= scale;
#pragma unroll
            for (int i = 0; i < 16; ++i) accv[i] *= scale;
            m_run = m_new;
        }
        l_run += ps;
        // weighted-key accumulation from the tile's register fragments (keys read ONCE)
#pragma unroll
        for (int i = 0; i < 8; ++i) {
            accv[i]     += p * bf2f(aK0[i]);
            accv[8 + i] += p * bf2f(aK1[i]);
        }
    };

    // ---- 13 tiles; depth-2 prefetch; unroll-by-2 keeps buffer indices static ----
#pragma unroll 1
    for (int i = 0; i < 6; ++i) {
        const int jt = i * 2;
        float4 c0 = pA0, c1 = pA1, c2 = pA2, c3 = pA3;
        {   // prefetch tile jt+2 into A (row clamp keeps it in-bounds; tail rows masked later)
            int row = (jt + 2) * 16 + col;
            row = row < 200 ? row : 199;
            const float* kr = kb + row * 64 + quad * 8;
            pA0 = *(const float4*)(kr);
            pA1 = *(const float4*)(kr + 4);
            pA2 = *(const float4*)(kr + 32);
            pA3 = *(const float4*)(kr + 36);
        }
        tile(jt, c0, c1, c2, c3);
        float4 d0 = pB0, d1 = pB1, d2 = pB2, d3 = pB3;
        {   // prefetch tile jt+3 into B (jt=10 fetches a dummy clamped tile; L1-hot, harmless)
            int row = (jt + 3) * 16 + col;
            row = row < 200 ? row : 199;
            const float* kr = kb + row * 64 + quad * 8;
            pB0 = *(const float4*)(kr);
            pB1 = *(const float4*)(kr + 4);
            pB2 = *(const float4*)(kr + 32);
            pB3 = *(const float4*)(kr + 36);
        }
        tile(jt + 1, d0, d1, d2, d3);
    }
    tile(12, pA0, pA1, pA2, pA3);         // tail tile (rows 192..207; 200+ masked)

    // ---- epilogue: cross-col reduce + normalize + store ----
    float inv = 1.f / l_run;
#pragma unroll
    for (int i = 0; i < 16; ++i) {
        float v = accv[i];
        v += __shfl_xor(v, 1);
        v += __shfl_xor(v, 2);
        v += __shfl_xor(v, 4);
        v += __shfl_xor(v, 8);
        accv[i] = v * inv;
    }
    if (col == 0) {
        float* op = out + (size_t)b * 64;
        *(float4*)(op + quad * 8)          = make_float4(accv[0],  accv[1],  accv[2],  accv[3]);
        *(float4*)(op + quad * 8 + 4)      = make_float4(accv[4],  accv[5],  accv[6],  accv[7]);
        *(float4*)(op + 32 + quad * 8)     = make_float4(accv[8],  accv[9],  accv[10], accv[11]);
        *(float4*)(op + 32 + quad * 8 + 4) = make_float4(accv[12], accv[13], accv[14], accv[15]);
    }
}

extern "C" void kernel_launch(void* const* d_in, const int* in_sizes, int n_in,
                              void* d_out, int out_size, void* d_ws, size_t ws_size,
                              hipStream_t stream) {
    const float* query    = (const float*)d_in[0];
    const float* keys     = (const float*)d_in[1];
    const int*   keys_len = (const int*)d_in[2];
    const float* W1       = (const float*)d_in[3];
    const float* b1       = (const float*)d_in[4];
    const float* W2       = (const float*)d_in[5];
    const float* b2       = (const float*)d_in[6];
    const float* W3       = (const float*)d_in[7];
    const float* b3       = (const float*)d_in[8];
    float* out            = (float*)d_out;

    const int B = in_sizes[1] / 12800;   // keys is (B,200,64)

    prep_all<<<dim3(1 + (B + 15) / 16), dim3(256), 0, stream>>>(W1, W2, query, b1, d_ws, B);
    attn_main<<<dim3((B + 3) / 4), dim3(256), 0, stream>>>(
        query, keys, keys_len, b2, W3, b3, d_ws, out, B);
}

// Round 5
// 317.638 us; speedup vs baseline: 1.5062x; 1.5062x over previous
//
#include <hip/hip_runtime.h>

typedef __attribute__((ext_vector_type(8))) short short8_t;
typedef __attribute__((ext_vector_type(4))) float f32x4;

#define MASK_VAL (-4294967295.0f)
#define NEG_BIG  (-1e30f)

__device__ __forceinline__ short f2bf(float x) {
    unsigned u;
    __builtin_memcpy(&u, &x, 4);
    u += 0x7FFFu + ((u >> 16) & 1u);   // round-to-nearest-even
    return (short)(u >> 16);
}
__device__ __forceinline__ float bf2f(short s) {
    unsigned u = ((unsigned)(unsigned short)s) << 16;
    float f;
    __builtin_memcpy(&f, &u, 4);
    return f;
}

// ---------------- prep (single launch): block 0 folds weights; blocks 1.. compute csAll
// ws layout (bytes):
//   0     : wkT   bf16 [64][64]  (W1b - W1c)^T   (row n, col k)
//   8192  : wdT   bf16 [64][64]  (W1d)^T
//   16384 : w2T   bf16 [32][64]  (W2)^T          (row o, col h)
//   36864 : csAll f32  [B][64]   b1 + q_b @ (W1a+W1c)
__global__ __launch_bounds__(256) void prep_all(
    const float* __restrict__ W1, const float* __restrict__ W2,
    const float* __restrict__ query, const float* __restrict__ b1,
    void* __restrict__ ws, int B)
{
    short* wkT = (short*)ws;
    short* wdT = wkT + 4096;
    short* w2T = wkT + 8192;
    float* csAll = (float*)((char*)ws + 36864);
    const int tid = threadIdx.x;

    if (blockIdx.x == 0) {
        for (int idx = tid; idx < 4096; idx += 256) {
            int n = idx & 63, k = idx >> 6;
            float a  = W1[4096  + idx];   // W1b[k][n]
            float c  = W1[8192  + idx];   // W1c[k][n]
            float d  = W1[12288 + idx];   // W1d[k][n]
            wkT[n * 64 + k] = f2bf(a - c);
            wdT[n * 64 + k] = f2bf(d);
        }
        for (int idx = tid; idx < 2048; idx += 256) {
            int o = idx & 31, h = idx >> 5;
            w2T[o * 64 + h] = f2bf(W2[idx]);   // W2[h][o], idx = h*32+o
        }
        return;
    }

    // csAll for 16 batches per block; wac built locally (no dependency on block 0)
    __shared__ float wacs[4096];     // 16 KB: W1a + W1c  (i-major)
    __shared__ float qsb[16 * 64];   // 4 KB
    __shared__ float b1s[64];
    const int g0 = (blockIdx.x - 1) * 16;
    for (int idx = tid; idx < 4096; idx += 256)
        wacs[idx] = W1[idx] + W1[8192 + idx];
    {
        int nb = B - g0; if (nb > 16) nb = 16;
        if (nb > 0)
            for (int i = tid; i < nb * 16; i += 256)
                ((float4*)qsb)[i] = ((const float4*)(query + (size_t)g0 * 64))[i];
    }
    if (tid < 64) b1s[tid] = b1[tid];
    __syncthreads();
    for (int o = tid; o < 1024; o += 256) {
        int bb = o >> 6, h = o & 63;
        if (g0 + bb >= B) continue;
        float acc = b1s[h];
#pragma unroll 16
        for (int i = 0; i < 64; ++i)
            acc += qsb[bb * 64 + i] * wacs[i * 64 + h];
        csAll[(size_t)(g0 + bb) * 64 + h] = acc;
    }
}

// ---------------- main: one WAVE per batch, online softmax, depth-2 key prefetch ----
// launch_bounds (256,2): VGPR cap 256. (256,3) caps at 170 and SPILLS (r4: WRITE_SIZE
// 79 MB of scratch, 252 us). Reported VGPR_Count is in 2-reg granules.
__global__ __launch_bounds__(256, 2) void attn_main(
    const float* __restrict__ query,    // (B,1,64)
    const float* __restrict__ keys,     // (B,200,64)
    const int*   __restrict__ keys_len, // (B,1)
    const float* __restrict__ b2,       // (32)
    const float* __restrict__ W3,       // (32,1)
    const float* __restrict__ b3,       // (1)
    const void*  __restrict__ ws,
    float* __restrict__ out,            // (B,1,64)
    int B)
{
    constexpr int STR = 72;   // shorts; 144 B row stride -> 16B-aligned b128 everywhere
    const short* wkT   = (const short*)ws;
    const short* wdT   = wkT + 4096;
    const short* w2T   = wkT + 8192;
    const float* csAll = (const float*)((const char*)ws + 36864);

    __shared__ short Bk[64 * STR];      // (W1b-W1c)^T
    __shared__ short Bd[64 * STR];      // W1d^T
    __shared__ short W2s[32 * STR];     // W2^T (rows o, cols h)
    __shared__ short h1w[4][16 * STR];  // per-wave h1 tile (C-layout -> B-frag layout)

    const int tid  = threadIdx.x;
    const int lane = tid & 63;
    const int wid  = tid >> 6;
    const int col  = lane & 15;
    const int quad = lane >> 4;
    const int b    = blockIdx.x * 4 + wid;
    const bool act = (b < B);

    // ---- cooperative staging (once per block = per 4 batches) ----
    for (int c = tid; c < 512; c += 256) {
        int r = c >> 3, ch = (c & 7) * 8;
        *(short8_t*)&Bk[r * STR + ch] = *(const short8_t*)(wkT + r * 64 + ch);
        *(short8_t*)&Bd[r * STR + ch] = *(const short8_t*)(wdT + r * 64 + ch);
    }
    {
        int r = tid >> 3, ch = (tid & 7) * 8;
        *(short8_t*)&W2s[r * STR + ch] = *(const short8_t*)(w2T + r * 64 + ch);
    }

    // ---- per-wave prologue ----
    const float* kb = nullptr;
    float4 pA0, pA1, pA2, pA3;          // prefetch buffer A (tile jt even)
    float4 pB0, pB1, pB2, pB3;          // prefetch buffer B (tile jt odd)
    float4 qv0, qv1, qv2, qv3;
    float4 b2qa, b2qb, w3qa, w3qb;
    float cs0 = 0.f, cs1 = 0.f, cs2 = 0.f, cs3 = 0.f, b3v = 0.f;
    if (act) {
        kb = keys + (size_t)b * 12800;
        {   // tile 0 (rows 0..15)
            const float* kr = kb + col * 64 + quad * 8;
            pA0 = *(const float4*)(kr);
            pA1 = *(const float4*)(kr + 4);
            pA2 = *(const float4*)(kr + 32);
            pA3 = *(const float4*)(kr + 36);
        }
        {   // tile 1 (rows 16..31)
            const float* kr = kb + (16 + col) * 64 + quad * 8;
            pB0 = *(const float4*)(kr);
            pB1 = *(const float4*)(kr + 4);
            pB2 = *(const float4*)(kr + 32);
            pB3 = *(const float4*)(kr + 36);
        }
        const float* qb = query + (size_t)b * 64;
        qv0 = *(const float4*)(qb + quad * 8);
        qv1 = *(const float4*)(qb + quad * 8 + 4);
        qv2 = *(const float4*)(qb + 32 + quad * 8);
        qv3 = *(const float4*)(qb + 32 + quad * 8 + 4);
        const float* cb = csAll + (size_t)b * 64;
        cs0 = cb[col]; cs1 = cb[16 + col]; cs2 = cb[32 + col]; cs3 = cb[48 + col];
        b2qa = *(const float4*)(b2 + quad * 4);
        b2qb = *(const float4*)(b2 + 16 + quad * 4);
        w3qa = *(const float4*)(W3 + quad * 4);
        w3qb = *(const float4*)(W3 + 16 + quad * 4);
        b3v  = b3[0];
    }
    __syncthreads();          // the ONLY block-wide barrier
    if (!act) return;

    const int len = keys_len[b];
    short* hw = h1w[wid];

    float m_run = NEG_BIG, l_run = 0.f;
    float accv[16];
#pragma unroll
    for (int i = 0; i < 16; ++i) accv[i] = 0.f;

    // ---- one tile of 16 rows: GEMM1 -> h1 -> GEMM2(swapped) -> score -> online SM ----
    auto tile = [&](int jt, float4 k0, float4 k1, float4 k2, float4 k3) {
        short8_t aK0, aK1, aQ0, aQ1;
        aK0[0] = f2bf(k0.x); aK0[1] = f2bf(k0.y); aK0[2] = f2bf(k0.z); aK0[3] = f2bf(k0.w);
        aK0[4] = f2bf(k1.x); aK0[5] = f2bf(k1.y); aK0[6] = f2bf(k1.z); aK0[7] = f2bf(k1.w);
        aK1[0] = f2bf(k2.x); aK1[1] = f2bf(k2.y); aK1[2] = f2bf(k2.z); aK1[3] = f2bf(k2.w);
        aK1[4] = f2bf(k3.x); aK1[5] = f2bf(k3.y); aK1[6] = f2bf(k3.z); aK1[7] = f2bf(k3.w);
        aQ0[0] = f2bf(k0.x * qv0.x); aQ0[1] = f2bf(k0.y * qv0.y);
        aQ0[2] = f2bf(k0.z * qv0.z); aQ0[3] = f2bf(k0.w * qv0.w);
        aQ0[4] = f2bf(k1.x * qv1.x); aQ0[5] = f2bf(k1.y * qv1.y);
        aQ0[6] = f2bf(k1.z * qv1.z); aQ0[7] = f2bf(k1.w * qv1.w);
        aQ1[0] = f2bf(k2.x * qv2.x); aQ1[1] = f2bf(k2.y * qv2.y);
        aQ1[2] = f2bf(k2.z * qv2.z); aQ1[3] = f2bf(k2.w * qv2.w);
        aQ1[4] = f2bf(k3.x * qv3.x); aQ1[5] = f2bf(k3.y * qv3.y);
        aQ1[6] = f2bf(k3.z * qv3.z); aQ1[7] = f2bf(k3.w * qv3.w);

        f32x4 acc[4] = {f32x4{0,0,0,0}, f32x4{0,0,0,0}, f32x4{0,0,0,0}, f32x4{0,0,0,0}};
#pragma unroll
        for (int nt = 0; nt < 4; ++nt) {
            const short* bp = &Bk[(nt * 16 + col) * STR + quad * 8];
            const short* dp = &Bd[(nt * 16 + col) * STR + quad * 8];
            acc[nt] = __builtin_amdgcn_mfma_f32_16x16x32_bf16(aK0, *(const short8_t*)bp,        acc[nt], 0, 0, 0);
            acc[nt] = __builtin_amdgcn_mfma_f32_16x16x32_bf16(aK1, *(const short8_t*)(bp + 32), acc[nt], 0, 0, 0);
            acc[nt] = __builtin_amdgcn_mfma_f32_16x16x32_bf16(aQ0, *(const short8_t*)dp,        acc[nt], 0, 0, 0);
            acc[nt] = __builtin_amdgcn_mfma_f32_16x16x32_bf16(aQ1, *(const short8_t*)(dp + 32), acc[nt], 0, 0, 0);
        }

        // relu + cs -> per-wave h1 tile (intra-wave LDS, program-order safe)
        float csv[4] = {cs0, cs1, cs2, cs3};
#pragma unroll
        for (int nt = 0; nt < 4; ++nt) {
            float cadd = csv[nt];
#pragma unroll
            for (int r = 0; r < 4; ++r)
                hw[(quad * 4 + r) * STR + nt * 16 + col] = f2bf(fmaxf(acc[nt][r] + cadd, 0.f));
        }

        // GEMM2 SWAPPED: A = W2^T frags (m = o_local), B = h1 frags (n = t)
        // -> D2 col = t = lane&15, reg r: o = quad*4 + r
        f32x4 acc2a = f32x4{0,0,0,0}, acc2b = f32x4{0,0,0,0};
#pragma unroll
        for (int ks = 0; ks < 2; ++ks) {
            short8_t h1f = *(const short8_t*)&hw[col * STR + ks * 32 + quad * 8];
            acc2a = __builtin_amdgcn_mfma_f32_16x16x32_bf16(
                *(const short8_t*)&W2s[col * STR + ks * 32 + quad * 8],        h1f, acc2a, 0, 0, 0);
            acc2b = __builtin_amdgcn_mfma_f32_16x16x32_bf16(
                *(const short8_t*)&W2s[(16 + col) * STR + ks * 32 + quad * 8], h1f, acc2b, 0, 0, 0);
        }

        // per-lane partial score over its 8 o-values, then 2 shuffles across quads
        float sp = 0.f;
#pragma unroll
        for (int r = 0; r < 4; ++r) {
            sp += fmaxf(acc2a[r] + b2qa[r], 0.f) * w3qa[r]
                + fmaxf(acc2b[r] + b2qb[r], 0.f) * w3qb[r];
        }
        sp += __shfl_xor(sp, 16);
        sp += __shfl_xor(sp, 32);
        float sv = sp + b3v;                  // every lane: score for row jt*16+col

        // ---- online softmax update ----
        int  row  = jt * 16 + col;
        bool vrow = row < 200;
        sv = (row < len) ? sv : MASK_VAL;     // mask (len==0 -> uniform, matches reference)
        float svm = vrow ? sv : NEG_BIG;
        svm = fmaxf(svm, __shfl_xor(svm, 1));
        svm = fmaxf(svm, __shfl_xor(svm, 2));
        svm = fmaxf(svm, __shfl_xor(svm, 4));
        svm = fmaxf(svm, __shfl_xor(svm, 8));
        float m_new = fmaxf(m_run, svm);
        float p = vrow ? __expf(sv - m_new) : 0.f;
        float ps = p;
        ps += __shfl_xor(ps, 1);
        ps += __shfl_xor(ps, 2);
        ps += __shfl_xor(ps, 4);
        ps += __shfl_xor(ps, 8);
        if (m_new > m_run) {                  // wave-uniform; rescale only when max grows
            float scale = __expf(m_run - m_new);
            l_run *= scale;
#pragma unroll
            for (int i = 0; i < 16; ++i) accv[i] *= scale;
            m_run = m_new;
        }
        l_run += ps;
        // weighted-key accumulation from the tile's register fragments (keys read ONCE)
#pragma unroll
        for (int i = 0; i < 8; ++i) {
            accv[i]     += p * bf2f(aK0[i]);
            accv[8 + i] += p * bf2f(aK1[i]);
        }
    };

    // ---- 13 tiles; depth-2 prefetch; unroll-by-2 keeps buffer indices static ----
#pragma unroll 1
    for (int i = 0; i < 6; ++i) {
        const int jt = i * 2;
        float4 c0 = pA0, c1 = pA1, c2 = pA2, c3 = pA3;
        {   // prefetch tile jt+2 into A (row clamp keeps it in-bounds; tail rows masked later)
            int row = (jt + 2) * 16 + col;
            row = row < 200 ? row : 199;
            const float* kr = kb + row * 64 + quad * 8;
            pA0 = *(const float4*)(kr);
            pA1 = *(const float4*)(kr + 4);
            pA2 = *(const float4*)(kr + 32);
            pA3 = *(const float4*)(kr + 36);
        }
        tile(jt, c0, c1, c2, c3);
        float4 d0 = pB0, d1 = pB1, d2 = pB2, d3 = pB3;
        {   // prefetch tile jt+3 into B (jt=10 fetches a dummy clamped tile; L1-hot, harmless)
            int row = (jt + 3) * 16 + col;
            row = row < 200 ? row : 199;
            const float* kr = kb + row * 64 + quad * 8;
            pB0 = *(const float4*)(kr);
            pB1 = *(const float4*)(kr + 4);
            pB2 = *(const float4*)(kr + 32);
            pB3 = *(const float4*)(kr + 36);
        }
        tile(jt + 1, d0, d1, d2, d3);
    }
    tile(12, pA0, pA1, pA2, pA3);         // tail tile (rows 192..207; 200+ masked)

    // ---- epilogue: cross-col reduce + normalize + store ----
    float inv = 1.f / l_run;
#pragma unroll
    for (int i = 0; i < 16; ++i) {
        float v = accv[i];
        v += __shfl_xor(v, 1);
        v += __shfl_xor(v, 2);
        v += __shfl_xor(v, 4);
        v += __shfl_xor(v, 8);
        accv[i] = v * inv;
    }
    if (col == 0) {
        float* op = out + (size_t)b * 64;
        *(float4*)(op + quad * 8)          = make_float4(accv[0],  accv[1],  accv[2],  accv[3]);
        *(float4*)(op + quad * 8 + 4)      = make_float4(accv[4],  accv[5],  accv[6],  accv[7]);
        *(float4*)(op + 32 + quad * 8)     = make_float4(accv[8],  accv[9],  accv[10], accv[11]);
        *(float4*)(op + 32 + quad * 8 + 4) = make_float4(accv[12], accv[13], accv[14], accv[15]);
    }
}

extern "C" void kernel_launch(void* const* d_in, const int* in_sizes, int n_in,
                              void* d_out, int out_size, void* d_ws, size_t ws_size,
                              hipStream_t stream) {
    const float* query    = (const float*)d_in[0];
    const float* keys     = (const float*)d_in[1];
    const int*   keys_len = (const int*)d_in[2];
    const float* W1       = (const float*)d_in[3];
    const float* b1       = (const float*)d_in[4];
    const float* W2       = (const float*)d_in[5];
    const float* b2       = (const float*)d_in[6];
    const float* W3       = (const float*)d_in[7];
    const float* b3       = (const float*)d_in[8];
    float* out            = (float*)d_out;

    const int B = in_sizes[1] / 12800;   // keys is (B,200,64)

    prep_all<<<dim3(1 + (B + 15) / 16), dim3(256), 0, stream>>>(W1, W2, query, b1, d_ws, B);
    attn_main<<<dim3((B + 3) / 4), dim3(256), 0, stream>>>(
        query, keys, keys_len, b2, W3, b3, d_ws, out, B);
}